// Round 10
// baseline (402.064 us; speedup 1.0000x reference)
//
#include <hip/hip_runtime.h>
#include <hip/hip_bf16.h>
#include <hip/hip_fp16.h>

#define N_NODES 100000
#define N_EDGES 3200000
#define N_GRAPHS 4096
#define N_REL 5
#define N_BASES 4
#define HID 32
#define SEG (N_NODES*N_REL)
#define DUMMY N_NODES            // extra node whose fp16 feature row is all-zero

#define NBUCK 392                // buckets of 256 dst nodes
#define BCAP  10240              // part-record capacity per bucket (mean 8163)
#define PBCAP 15360              // padded srcs capacity per bucket (mean ~12.9K)
#define NKEY  1280               // 256 nodes * 5 rels

typedef _Float16 half8 __attribute__((ext_vector_type(8)));
typedef float floatx4 __attribute__((ext_vector_type(4)));

// ---------------- CSR pass 1: partition edges into dst-range buckets ----------------
static __global__ __launch_bounds__(256) void k_part(const int* __restrict__ ei,
                                                     const int* __restrict__ et,
                                                     int* __restrict__ gcur,
                                                     unsigned long long* __restrict__ part) {
    __shared__ int hcnt[NBUCK];
    __shared__ int lbase[NBUCK];
    int t = threadIdx.x;
    for (int k = t; k < NBUCK; k += 256) hcnt[k] = 0;
    __syncthreads();
    int e0 = blockIdx.x * 4096;
    int src[16], bkt[16], lkey[16];
#pragma unroll
    for (int j = 0; j < 16; j++) {
        int e = e0 + j * 256 + t;
        if (e < N_EDGES) {
            int s = ei[e];
            int d = ei[N_EDGES + e];
            int r = et[e];
            src[j] = s; bkt[j] = d >> 8; lkey[j] = ((d & 255) * 5) + r;
            atomicAdd(&hcnt[bkt[j]], 1);
        } else bkt[j] = -1;
    }
    __syncthreads();
    for (int k = t; k < NBUCK; k += 256) lbase[k] = atomicAdd(&gcur[k], hcnt[k]);
    __syncthreads();
    for (int k = t; k < NBUCK; k += 256) hcnt[k] = 0;   // reuse as intra-block cursor
    __syncthreads();
#pragma unroll
    for (int j = 0; j < 16; j++) {
        if (bkt[j] >= 0) {
            int rank = atomicAdd(&hcnt[bkt[j]], 1);
            int p = lbase[bkt[j]] + rank;
            if (p < BCAP)
                part[(size_t)bkt[j] * BCAP + p] =
                    ((unsigned long long)(unsigned)lkey[j] << 32) | (unsigned)src[j];
        }
    }
}

// ---------------- CSR pass 2: per-bucket counting sort, runs PADDED to 8 ----------------
// 392 blocks, ~73 KB LDS -> 2 blocks/CU. srcs fully written to PBCAP (pad+tail
// = DUMMY) so any in-bucket read hits a valid index.
static __global__ __launch_bounds__(512) void k_bsort(const unsigned long long* __restrict__ part,
                                                      const int* __restrict__ gcur,
                                                      int* __restrict__ offs,
                                                      int* __restrict__ cnt,
                                                      int* __restrict__ srcs) {
    __shared__ int lhist[NKEY];      // 5 KB
    __shared__ int lscan[NKEY];      // 5 KB
    __shared__ int sscan[256];       // 1 KB
    __shared__ int lsrc[PBCAP];      // 60 KB
    int b = blockIdx.x;
    int t = threadIdx.x;
    int n = gcur[b]; if (n > BCAP) n = BCAP;
    const unsigned long long* reg = part + (size_t)b * BCAP;

    for (int k = t; k < NKEY; k += 512) lhist[k] = 0;
    __syncthreads();
    for (int i = t; i < n; i += 512)
        atomicAdd(&lhist[(int)(reg[i] >> 32)], 1);
    __syncthreads();

    // exclusive scan over PADDED counts (1280 = 256 threads x 5 keys)
    int loc[5]; int s5 = 0;
    if (t < 256) {
#pragma unroll
        for (int j = 0; j < 5; j++) { loc[j] = s5; s5 += (lhist[t * 5 + j] + 7) & ~7; }
        sscan[t] = s5;
    }
    __syncthreads();
    for (int off = 1; off < 256; off <<= 1) {
        int x = (t >= off && t < 256) ? sscan[t - off] : 0;
        __syncthreads();
        if (t < 256) sscan[t] += x;
        __syncthreads();
    }
    if (t < 256) {
        int excl = sscan[t] - s5;
#pragma unroll
        for (int j = 0; j < 5; j++) lscan[t * 5 + j] = excl + loc[j];
    }
    __syncthreads();
    int ptot = sscan[255]; if (ptot > PBCAP) ptot = PBCAP;

    int base = b * PBCAP;
    if (t < 256) {
#pragma unroll
        for (int j = 0; j < 5; j++) {
            int k = t * 5 + j;
            int segid = b * NKEY + k;
            if (segid < SEG) {
                cnt[segid]  = lhist[k];
                offs[segid] = base + lscan[k];
            }
        }
    }
    __syncthreads();
    // reset cursors + dummy-fill ENTIRE bucket region
    for (int k = t; k < NKEY; k += 512) lhist[k] = 0;
    for (int i = t; i < PBCAP; i += 512) lsrc[i] = DUMMY;
    __syncthreads();
    for (int i = t; i < n; i += 512) {
        unsigned long long u = reg[i];
        int k = (int)(u >> 32);
        int pos = lscan[k] + atomicAdd(&lhist[k], 1);
        if (pos < PBCAP) lsrc[pos] = (int)(u & 0xffffffffULL);
    }
    __syncthreads();
    for (int i = t; i < PBCAP; i += 512) srcs[base + i] = lsrc[i];
}

// ---------------- fp16 layer-0 table + dummy rows + srcs slack ----------------
static __global__ __launch_bounds__(256) void k_pad(const float* __restrict__ x,
                                                    __half* __restrict__ ht0,
                                                    __half* __restrict__ hall16,
                                                    int* __restrict__ srcs) {
    int tid = blockIdx.x * 256 + threadIdx.x;
    if (tid < (N_NODES + 1) * 32) {
        int nd = tid >> 5, ii = tid & 31;
        float v = (nd < N_NODES && ii < 4) ? x[(nd << 2) + ii] : 0.f;
        ht0[tid] = __float2half(v);
    } else {
        int r = tid - (N_NODES + 1) * 32;
        if (r < 128) hall16[N_NODES * 128 + r] = __float2half(0.f);  // dummy row
        else if (r < 144) srcs[NBUCK * PBCAP + (r - 128)] = DUMMY;   // global slack
    }
}

// ---------------- weight prep: fp16 MFMA B-fragments, 4 RGCN layers ----------------
// Per-layer block = 5*2*512 = 5120 halves. idx = ((l*5+s)*2+tile)*512 + lane*8+j
// holds W_l[k = s*32+(lane>>4)*8+j][o = tile*16+(lane&15)]. Exactly 20480 threads.
static __global__ __launch_bounds__(256) void k_wprepB(
    const float* __restrict__ ba0, const float* __restrict__ ro0,
    const float* __restrict__ ba1, const float* __restrict__ ro1,
    const float* __restrict__ ba2, const float* __restrict__ ro2,
    const float* __restrict__ ba3, const float* __restrict__ ro3,
    __half* __restrict__ Wb) {
    int idx = blockIdx.x * 256 + threadIdx.x;   // < 20480
    int j    = idx & 7;
    int lane = (idx >> 3) & 63;
    int tile = (idx >> 9) & 1;
    int ls   = idx >> 10;                       // l*5 + s, < 20
    int l    = ls / 5;
    int s    = ls - l * 5;
    const float* basis = (l == 0) ? ba0 : (l == 1) ? ba1 : (l == 2) ? ba2 : ba3;
    const float* root  = (l == 0) ? ro0 : (l == 1) ? ro1 : (l == 2) ? ro2 : ro3;
    int in_c = (l == 0) ? 4 : HID;
    int k = s * 32 + ((lane >> 4) << 3) + j;
    int o = tile * 16 + (lane & 15);
    float v;
    if (k < 128) {
        int b = k >> 5, ii = k & 31;
        v = (ii < in_c) ? basis[(b * in_c + ii) * HID + o] : 0.f;
    } else {
        int ii = k - 128;
        v = (ii < in_c) ? root[ii * HID + o] : 0.f;
    }
    Wb[idx] = __float2half(v);
}

// ---------------- weight prep: w1 [256x128] fp16 B-fragments for the MLP ----------
// idx = (tile*8 + s)*512 + lane*8 + j holds w1[k = s*32+(lane>>4)*8+j][o = tile*16+(lane&15)].
static __global__ __launch_bounds__(256) void k_wprepM(const float* __restrict__ w1,
                                                       __half* __restrict__ Wm) {
    int idx = blockIdx.x * 256 + threadIdx.x;   // < 32768
    int j    = idx & 7;
    int lane = (idx >> 3) & 63;
    int s    = (idx >> 9) & 7;
    int tile = idx >> 12;                       // < 8
    int k = s * 32 + ((lane >> 4) << 3) + j;
    int o = tile * 16 + (lane & 15);
    Wm[idx] = __float2half(w1[k * 128 + o]);
}

// ---------------- fused RGCN layer ----------------
// Phase 1: quarter-wave = 1 node, p = dim pair, __half2 dword gathers from the
// fp16 table (layer 0: ht0 stride 32; layers 1-3: a 32-dim band of hall16,
// stride 128 -> same 64B line per edge). 8-padded runs, per-run comp fold.
// Deposits K=160 aggregate as fp16 into sAgg16[16][176] (stride 176 halves ==
// 24 banks -> phase-1 stores exactly 2-way = free).
// Phase 2: [16x160]x[160x32] via 5x mfma_f32_16x16x32_f16 per 16-col tile;
// epilogue bias+tanh, single fp16 store into hall16 band.
template <int TSTRIDE>
static __global__ __launch_bounds__(256, 8) void k_layer(
    const __half2* __restrict__ tab, const int* __restrict__ offs,
    const int* __restrict__ cnt, const int* __restrict__ srcs,
    const float* __restrict__ comp, const __half* __restrict__ Wbl,
    const float* __restrict__ bias, __half* __restrict__ hall16, int hall_off) {
    __shared__ __align__(16) __half sAgg16[16 * 176];   // 5.5 KB
    constexpr int T2 = TSTRIDE / 2;
    int t = threadIdx.x;
    int wave = t >> 6, q = (t >> 4) & 3, p = t & 15;

    float4 cw0 = *(const float4*)(comp + 0);        // SGPR-resident
    float4 cw1 = *(const float4*)(comp + 4);
    float4 cw2 = *(const float4*)(comp + 8);
    float4 cw3 = *(const float4*)(comp + 12);
    float4 cw4 = *(const float4*)(comp + 16);

    int n = blockIdx.x * 16 + wave * 4 + q;         // N_NODES = 6250*16
    int s5 = n * N_REL;
    int oo[6], cc[5];
#pragma unroll
    for (int r = 0; r < 5; r++) { oo[r] = offs[s5 + r]; cc[r] = cnt[s5 + r]; }
    oo[5] = oo[4] + ((cc[4] + 7) & ~7);             // padded end

    __half2 selfh = tab[n * T2 + p];
    float a0x = 0.f, a0y = 0.f, a1x = 0.f, a1y = 0.f;
    float a2x = 0.f, a2y = 0.f, a3x = 0.f, a3y = 0.f;

#pragma unroll
    for (int r = 0; r < 5; r++) {
        int pR = oo[r], pr = oo[r + 1] - pR;
        const int* sp = srcs + pR;                  // 32B-aligned
        int4 e0 = *(const int4*)(sp);               // per-quad broadcast
        int4 e1 = *(const int4*)(sp + 4);
        __half2 g0 = tab[e0.x * T2 + p], g1 = tab[e0.y * T2 + p];
        __half2 g2 = tab[e0.z * T2 + p], g3 = tab[e0.w * T2 + p];
        __half2 g4 = tab[e1.x * T2 + p], g5 = tab[e1.y * T2 + p];
        __half2 g6 = tab[e1.z * T2 + p], g7 = tab[e1.w * T2 + p];
        __half2 sb = __hadd2(__hadd2(__hadd2(g0, g1), __hadd2(g2, g3)),
                             __hadd2(__hadd2(g4, g5), __hadd2(g6, g7)));
        float2 bf = __half22float2(sb);
        float Sx = bf.x, Sy = bf.y;
        for (int s8 = 8; s8 < pr; s8 += 8) {        // residual batches (~20%)
            int4 f0 = *(const int4*)(sp + s8);
            int4 f1 = *(const int4*)(sp + s8 + 4);
            __half2 h0 = tab[f0.x * T2 + p], h1 = tab[f0.y * T2 + p];
            __half2 h2 = tab[f0.z * T2 + p], h3 = tab[f0.w * T2 + p];
            __half2 h4 = tab[f1.x * T2 + p], h5 = tab[f1.y * T2 + p];
            __half2 h6 = tab[f1.z * T2 + p], h7 = tab[f1.w * T2 + p];
            __half2 rb = __hadd2(__hadd2(__hadd2(h0, h1), __hadd2(h2, h3)),
                                 __hadd2(__hadd2(h4, h5), __hadd2(h6, h7)));
            float2 rf = __half22float2(rb);
            Sx += rf.x; Sy += rf.y;
        }
        int cr = cc[r];
        float ic = (cr > 0) ? __builtin_amdgcn_rcpf((float)cr) : 0.f;
        float scx = Sx * ic, scy = Sy * ic;
        float4 cw = (r == 0) ? cw0 : (r == 1) ? cw1 : (r == 2) ? cw2
                  : (r == 3) ? cw3 : cw4;           // resolved at unroll
        a0x += cw.x * scx; a0y += cw.x * scy;
        a1x += cw.y * scx; a1y += cw.y * scy;
        a2x += cw.z * scx; a2y += cw.z * scy;
        a3x += cw.w * scx; a3y += cw.w * scy;
    }
    int nl = wave * 4 + q;
    __half2* row = (__half2*)(sAgg16 + nl * 176);   // k/2 index
    row[p]      = __float22half2_rn(make_float2(a0x, a0y));   // k = 0..31
    row[16 + p] = __float22half2_rn(make_float2(a1x, a1y));   // k = 32..63
    row[32 + p] = __float22half2_rn(make_float2(a2x, a2y));   // k = 64..95
    row[48 + p] = __float22half2_rn(make_float2(a3x, a3y));   // k = 96..127
    row[64 + p] = selfh;                                      // k = 128..159
    __syncthreads();

    // phase 2: [16x160] x [160x32] via 5x mfma_f32_16x16x32_f16 per tile
    if (wave < 2) {
        int lane = t & 63;
        floatx4 acc = {0.f, 0.f, 0.f, 0.f};
        const __half* aBase = sAgg16 + (lane & 15) * 176 + ((lane >> 4) << 3);
        const __half* bBase = Wbl + wave * 512 + lane * 8;
#pragma unroll
        for (int s = 0; s < 5; s++) {
            half8 a = *(const half8*)(aBase + s * 32);
            half8 b = *(const half8*)(bBase + s * 1024);
            acc = __builtin_amdgcn_mfma_f32_16x16x32_f16(a, b, acc, 0, 0, 0);
        }
        int o = wave * 16 + (lane & 15);
        float bi = bias[o];
#pragma unroll
        for (int r = 0; r < 4; r++) {
            int node = blockIdx.x * 16 + ((lane >> 4) << 2) + r;
            hall16[node * 128 + hall_off + o] = __float2half(tanhf(acc[r] + bi));
        }
    }
}

// ---------------- final MLP via MFMA: 16 graphs/block ----------------
// g[16][256] fp16 in LDS (stride 264 -> 2-way A reads). Each wave owns 2 of the
// 8 output col-tiles: 16 MFMAs. Epilogue: relu(z+b1) dot w2 via 16-lane
// shuffle reduce, cross-wave sum in LDS.
static __global__ __launch_bounds__(256) void k_mlp(
    const __half* __restrict__ hall16, const int* __restrict__ uidx,
    const int* __restrict__ iidx, const __half* __restrict__ Wm,
    const float* __restrict__ b1, const float* __restrict__ w2,
    const float* __restrict__ b2, float* __restrict__ out) {
    __shared__ __align__(16) __half sg[16 * 264];   // 8.25 KB
    __shared__ float sacc[4][16];
    int t = threadIdx.x, wave = t >> 6, lane = t & 63;
    int g0 = blockIdx.x * 16;
#pragma unroll
    for (int gg2 = 0; gg2 < 4; gg2++) {
        int gg = wave * 4 + gg2;
        int g = g0 + gg;
        int u = uidx[g], it = iidx[g];
        const __half2* hu = (const __half2*)(hall16 + u * 128);
        const __half2* hi = (const __half2*)(hall16 + it * 128);
        __half2* dst = (__half2*)(sg + gg * 264);
        dst[lane]      = hu[lane];
        dst[64 + lane] = hi[lane];
    }
    __syncthreads();
    floatx4 acc0 = {0.f, 0.f, 0.f, 0.f}, acc1 = {0.f, 0.f, 0.f, 0.f};
    const __half* aBase = sg + (lane & 15) * 264 + ((lane >> 4) << 3);
    const __half* bB0 = Wm + (wave * 2 + 0) * 4096 + lane * 8;
    const __half* bB1 = Wm + (wave * 2 + 1) * 4096 + lane * 8;
#pragma unroll
    for (int s = 0; s < 8; s++) {
        half8 a  = *(const half8*)(aBase + s * 32);
        half8 f0 = *(const half8*)(bB0 + s * 512);
        half8 f1 = *(const half8*)(bB1 + s * 512);
        acc0 = __builtin_amdgcn_mfma_f32_16x16x32_f16(a, f0, acc0, 0, 0, 0);
        acc1 = __builtin_amdgcn_mfma_f32_16x16x32_f16(a, f1, acc1, 0, 0, 0);
    }
    int o0 = wave * 32 + (lane & 15);
    int o1 = o0 + 16;
    float b10 = b1[o0], b11 = b1[o1], w20 = w2[o0], w21 = w2[o1];
#pragma unroll
    for (int r = 0; r < 4; r++) {
        float z0 = fmaxf(acc0[r] + b10, 0.f);
        float z1 = fmaxf(acc1[r] + b11, 0.f);
        float v = z0 * w20 + z1 * w21;
#pragma unroll
        for (int off = 1; off < 16; off <<= 1) v += __shfl_xor(v, off);
        if ((lane & 15) == 0) sacc[wave][((lane >> 4) << 2) + r] = v;
    }
    __syncthreads();
    if (t < 16)
        out[g0 + t] = sacc[0][t] + sacc[1][t] + sacc[2][t] + sacc[3][t] + b2[0];
}

// ---------------- launcher ----------------
extern "C" void kernel_launch(void* const* d_in, const int* in_sizes, int n_in,
                              void* d_out, int out_size, void* d_ws, size_t ws_size,
                              hipStream_t stream) {
    const float* x  = (const float*)d_in[0];
    const int*   ei = (const int*)d_in[1];
    const int*   et = (const int*)d_in[2];
    const int*   ui = (const int*)d_in[3];
    const int*   ii = (const int*)d_in[4];
    const float* w1 = (const float*)d_in[21];
    const float* b1 = (const float*)d_in[22];
    const float* w2 = (const float*)d_in[23];
    const float* b2 = (const float*)d_in[24];

    // workspace layout (bytes, 128-aligned). Total ~66.7 MB; guard proven in R1.
    char* ws = (char*)d_ws;
    if (ws_size < 92167680UL) return;
    int*    gcur   = (int*)(ws + 0);              // [392]
    int*    offs   = (int*)(ws + 2048);           // [500000]
    int*    cnt    = (int*)(ws + 2002176);        // [500000]
    int*    srcs   = (int*)(ws + 4002304);        // [392*15360] + 16 slack
    __half* ht0    = (__half*)(ws + 28086912);    // [100001*32] fp16
    __half* Wb     = (__half*)(ws + 34487040);    // [20480] fp16 RGCN B-frags
    __half* Wm     = (__half*)(ws + 34528128);    // [32768] fp16 MLP B-frags
    __half* hall16 = (__half*)(ws + 34593792);    // [100001*128] fp16
    unsigned long long* part = (unsigned long long*)hall16;  // alias 32.1 MB (dead later)

    hipMemsetAsync(gcur, 0, NBUCK * 4, stream);

    k_part<<<782, 256, 0, stream>>>(ei, et, gcur, part);
    k_bsort<<<NBUCK, 512, 0, stream>>>(part, gcur, offs, cnt, srcs);
    k_pad<<<12501, 256, 0, stream>>>(x, ht0, hall16, srcs);
    k_wprepB<<<80, 256, 0, stream>>>(           // 80*256 = 20480 = 4 layers * 5120
        (const float*)d_in[5],  (const float*)d_in[7],
        (const float*)d_in[9],  (const float*)d_in[11],
        (const float*)d_in[13], (const float*)d_in[15],
        (const float*)d_in[17], (const float*)d_in[19], Wb);
    k_wprepM<<<128, 256, 0, stream>>>(w1, Wm);  // 128*256 = 32768

    for (int l = 0; l < 4; l++) {
        const float* comp = (const float*)d_in[6 + 4 * l];
        const float* bias = (const float*)d_in[8 + 4 * l];
        if (l == 0)
            k_layer<32><<<6250, 256, 0, stream>>>((const __half2*)ht0, offs, cnt,
                                                  srcs, comp, Wb, bias, hall16, 0);
        else
            k_layer<128><<<6250, 256, 0, stream>>>(
                (const __half2*)(hall16 + (l - 1) * 32), offs, cnt, srcs, comp,
                Wb + l * 5120, bias, hall16, l * 32);
    }
    k_mlp<<<256, 256, 0, stream>>>(hall16, ui, ii, Wm, b1, w2, b2, (float*)d_out);
}

// Round 11
// 368.247 us; speedup vs baseline: 1.0918x; 1.0918x over previous
//
#include <hip/hip_runtime.h>
#include <hip/hip_bf16.h>
#include <hip/hip_fp16.h>

#define N_NODES 100000
#define N_EDGES 3200000
#define N_GRAPHS 4096
#define N_REL 5
#define N_BASES 4
#define HID 32
#define SEG (N_NODES*N_REL)
#define DUMMY N_NODES            // extra node whose fp16 feature row is all-zero

#define NBUCK 392                // buckets of 256 dst nodes
#define BCAP  10240              // part-record capacity per bucket (mean 8163)
#define PBCAP 15360              // padded srcs capacity per bucket (mean ~12.9K)
#define NKEY  1280               // 256 nodes * 5 rels

typedef _Float16 half8 __attribute__((ext_vector_type(8)));
typedef float floatx4 __attribute__((ext_vector_type(4)));

// ---------------- CSR pass 1: partition edges into dst-range buckets ----------------
static __global__ __launch_bounds__(256) void k_part(const int* __restrict__ ei,
                                                     const int* __restrict__ et,
                                                     int* __restrict__ gcur,
                                                     unsigned long long* __restrict__ part) {
    __shared__ int hcnt[NBUCK];
    __shared__ int lbase[NBUCK];
    int t = threadIdx.x;
    for (int k = t; k < NBUCK; k += 256) hcnt[k] = 0;
    __syncthreads();
    int e0 = blockIdx.x * 4096;
    int src[16], bkt[16], lkey[16];
#pragma unroll
    for (int j = 0; j < 16; j++) {
        int e = e0 + j * 256 + t;
        if (e < N_EDGES) {
            int s = ei[e];
            int d = ei[N_EDGES + e];
            int r = et[e];
            src[j] = s; bkt[j] = d >> 8; lkey[j] = ((d & 255) * 5) + r;
            atomicAdd(&hcnt[bkt[j]], 1);
        } else bkt[j] = -1;
    }
    __syncthreads();
    for (int k = t; k < NBUCK; k += 256) lbase[k] = atomicAdd(&gcur[k], hcnt[k]);
    __syncthreads();
    for (int k = t; k < NBUCK; k += 256) hcnt[k] = 0;   // reuse as intra-block cursor
    __syncthreads();
#pragma unroll
    for (int j = 0; j < 16; j++) {
        if (bkt[j] >= 0) {
            int rank = atomicAdd(&hcnt[bkt[j]], 1);
            int p = lbase[bkt[j]] + rank;
            if (p < BCAP)
                part[(size_t)bkt[j] * BCAP + p] =
                    ((unsigned long long)(unsigned)lkey[j] << 32) | (unsigned)src[j];
        }
    }
}

// ---------------- CSR pass 2: per-bucket counting sort, runs PADDED to 8 ----------------
// 392 blocks, ~73 KB LDS -> 2 blocks/CU. srcs fully written to PBCAP (pad+tail
// = DUMMY) so any in-bucket read hits a valid index.
static __global__ __launch_bounds__(512) void k_bsort(const unsigned long long* __restrict__ part,
                                                      const int* __restrict__ gcur,
                                                      int* __restrict__ offs,
                                                      int* __restrict__ cnt,
                                                      int* __restrict__ srcs) {
    __shared__ int lhist[NKEY];      // 5 KB
    __shared__ int lscan[NKEY];      // 5 KB
    __shared__ int sscan[256];       // 1 KB
    __shared__ int lsrc[PBCAP];      // 60 KB
    int b = blockIdx.x;
    int t = threadIdx.x;
    int n = gcur[b]; if (n > BCAP) n = BCAP;
    const unsigned long long* reg = part + (size_t)b * BCAP;

    for (int k = t; k < NKEY; k += 512) lhist[k] = 0;
    __syncthreads();
    for (int i = t; i < n; i += 512)
        atomicAdd(&lhist[(int)(reg[i] >> 32)], 1);
    __syncthreads();

    // exclusive scan over PADDED counts (1280 = 256 threads x 5 keys)
    int loc[5]; int s5 = 0;
    if (t < 256) {
#pragma unroll
        for (int j = 0; j < 5; j++) { loc[j] = s5; s5 += (lhist[t * 5 + j] + 7) & ~7; }
        sscan[t] = s5;
    }
    __syncthreads();
    for (int off = 1; off < 256; off <<= 1) {
        int x = (t >= off && t < 256) ? sscan[t - off] : 0;
        __syncthreads();
        if (t < 256) sscan[t] += x;
        __syncthreads();
    }
    if (t < 256) {
        int excl = sscan[t] - s5;
#pragma unroll
        for (int j = 0; j < 5; j++) lscan[t * 5 + j] = excl + loc[j];
    }
    __syncthreads();

    int base = b * PBCAP;
    if (t < 256) {
#pragma unroll
        for (int j = 0; j < 5; j++) {
            int k = t * 5 + j;
            int segid = b * NKEY + k;
            if (segid < SEG) {
                cnt[segid]  = lhist[k];
                offs[segid] = base + lscan[k];
            }
        }
    }
    __syncthreads();
    // reset cursors + dummy-fill ENTIRE bucket region
    for (int k = t; k < NKEY; k += 512) lhist[k] = 0;
    for (int i = t; i < PBCAP; i += 512) lsrc[i] = DUMMY;
    __syncthreads();
    for (int i = t; i < n; i += 512) {
        unsigned long long u = reg[i];
        int k = (int)(u >> 32);
        int pos = lscan[k] + atomicAdd(&lhist[k], 1);
        if (pos < PBCAP) lsrc[pos] = (int)(u & 0xffffffffULL);
    }
    __syncthreads();
    for (int i = t; i < PBCAP; i += 512) srcs[base + i] = lsrc[i];
}

// ---------------- fp16 layer-0 table + dummy rows of ht1..ht4 + srcs slack -------
static __global__ __launch_bounds__(256) void k_pad(const float* __restrict__ x,
                                                    __half* __restrict__ ht0,
                                                    __half* __restrict__ ht1,
                                                    __half* __restrict__ ht2,
                                                    __half* __restrict__ ht3,
                                                    __half* __restrict__ ht4,
                                                    int* __restrict__ srcs) {
    int tid = blockIdx.x * 256 + threadIdx.x;
    if (tid < (N_NODES + 1) * 32) {
        int nd = tid >> 5, ii = tid & 31;
        float v = (nd < N_NODES && ii < 4) ? x[(nd << 2) + ii] : 0.f;
        ht0[tid] = __float2half(v);
    } else {
        int r = tid - (N_NODES + 1) * 32;
        if (r < 128) {
            __half* hp = (r < 32) ? ht1 : (r < 64) ? ht2 : (r < 96) ? ht3 : ht4;
            hp[N_NODES * 32 + (r & 31)] = __float2half(0.f);   // dummy rows
        } else if (r < 144) srcs[NBUCK * PBCAP + (r - 128)] = DUMMY;  // slack
    }
}

// ---------------- weight prep: fp16 MFMA B-fragments, 4 RGCN layers ----------------
// Per-layer block = 5*2*512 = 5120 halves. idx = ((l*5+s)*2+tile)*512 + lane*8+j
// holds W_l[k = s*32+(lane>>4)*8+j][o = tile*16+(lane&15)]. Exactly 20480 threads.
static __global__ __launch_bounds__(256) void k_wprepB(
    const float* __restrict__ ba0, const float* __restrict__ ro0,
    const float* __restrict__ ba1, const float* __restrict__ ro1,
    const float* __restrict__ ba2, const float* __restrict__ ro2,
    const float* __restrict__ ba3, const float* __restrict__ ro3,
    __half* __restrict__ Wb) {
    int idx = blockIdx.x * 256 + threadIdx.x;   // < 20480
    int j    = idx & 7;
    int lane = (idx >> 3) & 63;
    int tile = (idx >> 9) & 1;
    int ls   = idx >> 10;                       // l*5 + s, < 20
    int l    = ls / 5;
    int s    = ls - l * 5;
    const float* basis = (l == 0) ? ba0 : (l == 1) ? ba1 : (l == 2) ? ba2 : ba3;
    const float* root  = (l == 0) ? ro0 : (l == 1) ? ro1 : (l == 2) ? ro2 : ro3;
    int in_c = (l == 0) ? 4 : HID;
    int k = s * 32 + ((lane >> 4) << 3) + j;
    int o = tile * 16 + (lane & 15);
    float v;
    if (k < 128) {
        int b = k >> 5, ii = k & 31;
        v = (ii < in_c) ? basis[(b * in_c + ii) * HID + o] : 0.f;
    } else {
        int ii = k - 128;
        v = (ii < in_c) ? root[ii * HID + o] : 0.f;
    }
    Wb[idx] = __float2half(v);
}

// ---------------- weight prep: w1 [256x128] fp16 B-fragments for the MLP ----------
static __global__ __launch_bounds__(256) void k_wprepM(const float* __restrict__ w1,
                                                       __half* __restrict__ Wm) {
    int idx = blockIdx.x * 256 + threadIdx.x;   // < 32768
    int j    = idx & 7;
    int lane = (idx >> 3) & 63;
    int s    = (idx >> 9) & 7;
    int tile = idx >> 12;                       // < 8
    int k = s * 32 + ((lane >> 4) << 3) + j;
    int o = tile * 16 + (lane & 15);
    Wm[idx] = __float2half(w1[k * 128 + o]);
}

// ---------------- fused RGCN layer ----------------
// Phase 1: quarter-wave = 1 node, p = dim pair, __half2 dword gathers from a
// DENSE fp16 table (stride 32: one node row = one 64B line -> max L2 density).
// 8-padded runs, per-run comp fold. Deposits K=160 aggregate as fp16 into
// sAgg16[16][176].
// Phase 2: [16x160]x[160x32] via 5x mfma_f32_16x16x32_f16 per 16-col tile;
// epilogue bias+tanh, single dense fp16 store (hout).
static __global__ __launch_bounds__(256, 8) void k_layer(
    const __half2* __restrict__ tab, const int* __restrict__ offs,
    const int* __restrict__ cnt, const int* __restrict__ srcs,
    const float* __restrict__ comp, const __half* __restrict__ Wbl,
    const float* __restrict__ bias, __half* __restrict__ hout) {
    __shared__ __align__(16) __half sAgg16[16 * 176];   // 5.5 KB
    int t = threadIdx.x;
    int wave = t >> 6, q = (t >> 4) & 3, p = t & 15;

    float4 cw0 = *(const float4*)(comp + 0);        // SGPR-resident
    float4 cw1 = *(const float4*)(comp + 4);
    float4 cw2 = *(const float4*)(comp + 8);
    float4 cw3 = *(const float4*)(comp + 12);
    float4 cw4 = *(const float4*)(comp + 16);

    int n = blockIdx.x * 16 + wave * 4 + q;         // N_NODES = 6250*16
    int s5 = n * N_REL;
    int oo[6], cc[5];
#pragma unroll
    for (int r = 0; r < 5; r++) { oo[r] = offs[s5 + r]; cc[r] = cnt[s5 + r]; }
    oo[5] = oo[4] + ((cc[4] + 7) & ~7);             // padded end

    __half2 selfh = tab[n * 16 + p];
    float a0x = 0.f, a0y = 0.f, a1x = 0.f, a1y = 0.f;
    float a2x = 0.f, a2y = 0.f, a3x = 0.f, a3y = 0.f;

#pragma unroll
    for (int r = 0; r < 5; r++) {
        int pR = oo[r], pr = oo[r + 1] - pR;
        const int* sp = srcs + pR;                  // 32B-aligned
        int4 e0 = *(const int4*)(sp);               // per-quad broadcast
        int4 e1 = *(const int4*)(sp + 4);
        __half2 g0 = tab[e0.x * 16 + p], g1 = tab[e0.y * 16 + p];
        __half2 g2 = tab[e0.z * 16 + p], g3 = tab[e0.w * 16 + p];
        __half2 g4 = tab[e1.x * 16 + p], g5 = tab[e1.y * 16 + p];
        __half2 g6 = tab[e1.z * 16 + p], g7 = tab[e1.w * 16 + p];
        __half2 sb = __hadd2(__hadd2(__hadd2(g0, g1), __hadd2(g2, g3)),
                             __hadd2(__hadd2(g4, g5), __hadd2(g6, g7)));
        float2 bf = __half22float2(sb);
        float Sx = bf.x, Sy = bf.y;
        for (int s8 = 8; s8 < pr; s8 += 8) {        // residual batches (~20%)
            int4 f0 = *(const int4*)(sp + s8);
            int4 f1 = *(const int4*)(sp + s8 + 4);
            __half2 h0 = tab[f0.x * 16 + p], h1 = tab[f0.y * 16 + p];
            __half2 h2 = tab[f0.z * 16 + p], h3 = tab[f0.w * 16 + p];
            __half2 h4 = tab[f1.x * 16 + p], h5 = tab[f1.y * 16 + p];
            __half2 h6 = tab[f1.z * 16 + p], h7 = tab[f1.w * 16 + p];
            __half2 rb = __hadd2(__hadd2(__hadd2(h0, h1), __hadd2(h2, h3)),
                                 __hadd2(__hadd2(h4, h5), __hadd2(h6, h7)));
            float2 rf = __half22float2(rb);
            Sx += rf.x; Sy += rf.y;
        }
        int cr = cc[r];
        float ic = (cr > 0) ? __builtin_amdgcn_rcpf((float)cr) : 0.f;
        float scx = Sx * ic, scy = Sy * ic;
        float4 cw = (r == 0) ? cw0 : (r == 1) ? cw1 : (r == 2) ? cw2
                  : (r == 3) ? cw3 : cw4;           // resolved at unroll
        a0x += cw.x * scx; a0y += cw.x * scy;
        a1x += cw.y * scx; a1y += cw.y * scy;
        a2x += cw.z * scx; a2y += cw.z * scy;
        a3x += cw.w * scx; a3y += cw.w * scy;
    }
    int nl = wave * 4 + q;
    __half2* row = (__half2*)(sAgg16 + nl * 176);   // k/2 index
    row[p]      = __float22half2_rn(make_float2(a0x, a0y));   // k = 0..31
    row[16 + p] = __float22half2_rn(make_float2(a1x, a1y));   // k = 32..63
    row[32 + p] = __float22half2_rn(make_float2(a2x, a2y));   // k = 64..95
    row[48 + p] = __float22half2_rn(make_float2(a3x, a3y));   // k = 96..127
    row[64 + p] = selfh;                                      // k = 128..159
    __syncthreads();

    // phase 2: [16x160] x [160x32] via 5x mfma_f32_16x16x32_f16 per tile
    if (wave < 2) {
        int lane = t & 63;
        floatx4 acc = {0.f, 0.f, 0.f, 0.f};
        const __half* aBase = sAgg16 + (lane & 15) * 176 + ((lane >> 4) << 3);
        const __half* bBase = Wbl + wave * 512 + lane * 8;
#pragma unroll
        for (int s = 0; s < 5; s++) {
            half8 a = *(const half8*)(aBase + s * 32);
            half8 b = *(const half8*)(bBase + s * 1024);
            acc = __builtin_amdgcn_mfma_f32_16x16x32_f16(a, b, acc, 0, 0, 0);
        }
        int o = wave * 16 + (lane & 15);
        float bi = bias[o];
#pragma unroll
        for (int r = 0; r < 4; r++) {
            int node = blockIdx.x * 16 + ((lane >> 4) << 2) + r;
            hout[node * 32 + o] = __float2half(tanhf(acc[r] + bi));
        }
    }
}

// ---------------- final MLP via MFMA: 16 graphs/block ----------------
// g-vector concat gathered straight from the 4 dense tables: lane = (table
// lt = lane>>4, dim-pair lp = lane&15) -> coalesced 64B chunks. MFMA as R10.
static __global__ __launch_bounds__(256) void k_mlp(
    const __half* __restrict__ h1, const __half* __restrict__ h2,
    const __half* __restrict__ h3, const __half* __restrict__ h4,
    const int* __restrict__ uidx, const int* __restrict__ iidx,
    const __half* __restrict__ Wm, const float* __restrict__ b1,
    const float* __restrict__ w2, const float* __restrict__ b2,
    float* __restrict__ out) {
    __shared__ __align__(16) __half sg[16 * 264];   // 8.25 KB
    __shared__ float sacc[4][16];
    int t = threadIdx.x, wave = t >> 6, lane = t & 63;
    int g0 = blockIdx.x * 16;
    int lt = lane >> 4, lp = lane & 15;
    const __half* htab = (lt == 0) ? h1 : (lt == 1) ? h2 : (lt == 2) ? h3 : h4;
#pragma unroll
    for (int gg2 = 0; gg2 < 4; gg2++) {
        int gg = wave * 4 + gg2;
        int g = g0 + gg;
        int u = uidx[g], it = iidx[g];
        __half2* dst = (__half2*)(sg + gg * 264);
        dst[lt * 16 + lp]      = ((const __half2*)(htab + u * 32))[lp];
        dst[64 + lt * 16 + lp] = ((const __half2*)(htab + it * 32))[lp];
    }
    __syncthreads();
    floatx4 acc0 = {0.f, 0.f, 0.f, 0.f}, acc1 = {0.f, 0.f, 0.f, 0.f};
    const __half* aBase = sg + (lane & 15) * 264 + ((lane >> 4) << 3);
    const __half* bB0 = Wm + (wave * 2 + 0) * 4096 + lane * 8;
    const __half* bB1 = Wm + (wave * 2 + 1) * 4096 + lane * 8;
#pragma unroll
    for (int s = 0; s < 8; s++) {
        half8 a  = *(const half8*)(aBase + s * 32);
        half8 f0 = *(const half8*)(bB0 + s * 512);
        half8 f1 = *(const half8*)(bB1 + s * 512);
        acc0 = __builtin_amdgcn_mfma_f32_16x16x32_f16(a, f0, acc0, 0, 0, 0);
        acc1 = __builtin_amdgcn_mfma_f32_16x16x32_f16(a, f1, acc1, 0, 0, 0);
    }
    int o0 = wave * 32 + (lane & 15);
    int o1 = o0 + 16;
    float b10 = b1[o0], b11 = b1[o1], w20 = w2[o0], w21 = w2[o1];
#pragma unroll
    for (int r = 0; r < 4; r++) {
        float z0 = fmaxf(acc0[r] + b10, 0.f);
        float z1 = fmaxf(acc1[r] + b11, 0.f);
        float v = z0 * w20 + z1 * w21;
#pragma unroll
        for (int off = 1; off < 16; off <<= 1) v += __shfl_xor(v, off);
        if ((lane & 15) == 0) sacc[wave][((lane >> 4) << 2) + r] = v;
    }
    __syncthreads();
    if (t < 16)
        out[g0 + t] = sacc[0][t] + sacc[1][t] + sacc[2][t] + sacc[3][t] + b2[0];
}

// ---------------- launcher ----------------
extern "C" void kernel_launch(void* const* d_in, const int* in_sizes, int n_in,
                              void* d_out, int out_size, void* d_ws, size_t ws_size,
                              hipStream_t stream) {
    const float* x  = (const float*)d_in[0];
    const int*   ei = (const int*)d_in[1];
    const int*   et = (const int*)d_in[2];
    const int*   ui = (const int*)d_in[3];
    const int*   ii = (const int*)d_in[4];
    const float* w1 = (const float*)d_in[21];
    const float* b1 = (const float*)d_in[22];
    const float* w2 = (const float*)d_in[23];
    const float* b2 = (const float*)d_in[24];

    // workspace layout (bytes, 128-aligned). Total ~66.7 MB; guard proven in R1.
    char* ws = (char*)d_ws;
    if (ws_size < 92167680UL) return;
    int*    gcur = (int*)(ws + 0);              // [392]
    int*    offs = (int*)(ws + 2048);           // [500000]
    int*    cnt  = (int*)(ws + 2002176);        // [500000]
    int*    srcs = (int*)(ws + 4002304);        // [392*15360] + 16 slack
    __half* Wb   = (__half*)(ws + 28086912);    // [20480] fp16 RGCN B-frags
    __half* Wm   = (__half*)(ws + 28127872);    // [32768] fp16 MLP B-frags
    __half* ht0  = (__half*)(ws + 28193536);    // [100001*32] fp16 dense
    __half* ht1  = (__half*)(ws + 34593664);    // [100001*32]
    __half* ht2  = (__half*)(ws + 40993792);    // [100001*32]
    __half* ht3  = (__half*)(ws + 47393920);    // [100001*32]
    __half* ht4  = (__half*)(ws + 53794048);    // [100001*32], ends 60.2 MB
    // part aliases ht1..ht4 + tail (dead after k_bsort; layers run later)
    unsigned long long* part = (unsigned long long*)(ws + 34593664);  // 32.1 MB

    hipMemsetAsync(gcur, 0, NBUCK * 4, stream);

    k_part<<<782, 256, 0, stream>>>(ei, et, gcur, part);
    k_bsort<<<NBUCK, 512, 0, stream>>>(part, gcur, offs, cnt, srcs);
    k_pad<<<12501, 256, 0, stream>>>(x, ht0, ht1, ht2, ht3, ht4, srcs);
    k_wprepB<<<80, 256, 0, stream>>>(           // 80*256 = 20480 = 4 layers * 5120
        (const float*)d_in[5],  (const float*)d_in[7],
        (const float*)d_in[9],  (const float*)d_in[11],
        (const float*)d_in[13], (const float*)d_in[15],
        (const float*)d_in[17], (const float*)d_in[19], Wb);
    k_wprepM<<<128, 256, 0, stream>>>(w1, Wm);  // 128*256 = 32768

    __half* tabs[5] = {ht0, ht1, ht2, ht3, ht4};
    for (int l = 0; l < 4; l++) {
        const float* comp = (const float*)d_in[6 + 4 * l];
        const float* bias = (const float*)d_in[8 + 4 * l];
        k_layer<<<6250, 256, 0, stream>>>((const __half2*)tabs[l], offs, cnt,
                                          srcs, comp, Wb + l * 5120, bias,
                                          tabs[l + 1]);
    }
    k_mlp<<<256, 256, 0, stream>>>(ht1, ht2, ht3, ht4, ui, ii, Wm, b1, w2, b2,
                                   (float*)d_out);
}

// Round 12
// 353.499 us; speedup vs baseline: 1.1374x; 1.0417x over previous
//
#include <hip/hip_runtime.h>
#include <hip/hip_bf16.h>
#include <hip/hip_fp16.h>

#define N_NODES 100000
#define N_EDGES 3200000
#define N_GRAPHS 4096
#define N_REL 5
#define N_BASES 4
#define HID 32
#define SEG (N_NODES*N_REL)
#define DUMMY N_NODES            // extra node whose fp16 feature row is all-zero

#define NBUCK 392                // buckets of 256 dst nodes
#define BCAP  10240              // part-record capacity per bucket (mean 8163)
#define PBCAP 15360              // padded srcs capacity per bucket (mean ~12.9K)
#define NKEY  1280               // 256 nodes * 5 rels
#define PTILE 8192               // edges per k_part block

typedef _Float16 half8 __attribute__((ext_vector_type(8)));
typedef float floatx4 __attribute__((ext_vector_type(4)));

// ---------------- CSR pass 1: partition edges into dst-range buckets ----------------
// 3-pass in-block counting sort: LDS histogram -> bucket-contiguous LDS staging
// -> sequential copy-out. Each bucket's ~21-record run is written by consecutive
// threads to consecutive addresses (near-perfect write combining), vs R11's
// interleaved 8B scatters (3.6x write amplification).
static __global__ __launch_bounds__(256) void k_part(const int* __restrict__ ei,
                                                     const int* __restrict__ et,
                                                     int* __restrict__ gcur,
                                                     unsigned long long* __restrict__ part) {
    __shared__ unsigned long long stage[PTILE];     // 64 KB
    __shared__ int hist[NBUCK];
    __shared__ int lofs[NBUCK];
    __shared__ int lbase[NBUCK];
    __shared__ int sscan[256];
    int t = threadIdx.x;
    int e0 = blockIdx.x * PTILE;
    int tile_n = N_EDGES - e0; if (tile_n > PTILE) tile_n = PTILE;

    for (int k = t; k < NBUCK; k += 256) hist[k] = 0;
    __syncthreads();
    // pass A: histogram of dst buckets (dst re-read in pass B hits L2)
    for (int j = 0; j < PTILE / 256; j++) {
        int e = e0 + j * 256 + t;
        if (e < N_EDGES) atomicAdd(&hist[ei[N_EDGES + e] >> 8], 1);
    }
    __syncthreads();
    // exclusive scan over 392 buckets: thread t owns slots 2t, 2t+1
    int h0 = (2 * t     < NBUCK) ? hist[2 * t]     : 0;
    int h1 = (2 * t + 1 < NBUCK) ? hist[2 * t + 1] : 0;
    int s2 = h0 + h1;
    sscan[t] = s2;
    __syncthreads();
    for (int off = 1; off < 256; off <<= 1) {
        int xv = (t >= off) ? sscan[t - off] : 0;
        __syncthreads();
        sscan[t] += xv;
        __syncthreads();
    }
    int excl = sscan[t] - s2;
    if (2 * t     < NBUCK) lofs[2 * t]     = excl;
    if (2 * t + 1 < NBUCK) lofs[2 * t + 1] = excl + h0;
    // reserve global space per bucket
    for (int k = t; k < NBUCK; k += 256) lbase[k] = atomicAdd(&gcur[k], hist[k]);
    __syncthreads();
    for (int k = t; k < NBUCK; k += 256) hist[k] = 0;   // reuse as cursor
    __syncthreads();
    // pass B: scatter into bucket-ordered LDS staging
    for (int j = 0; j < PTILE / 256; j++) {
        int e = e0 + j * 256 + t;
        if (e < N_EDGES) {
            int s = ei[e];
            int d = ei[N_EDGES + e];
            int r = et[e];
            int bkt = d >> 8;
            int lkey = ((d & 255) * 5) + r;
            int rank = atomicAdd(&hist[bkt], 1);
            stage[lofs[bkt] + rank] =
                ((unsigned long long)(unsigned)((bkt << 16) | lkey) << 32) | (unsigned)s;
        }
    }
    __syncthreads();
    // pass C: sequential copy-out — per-bucket runs land coalesced
    for (int i = t; i < tile_n; i += 256) {
        unsigned long long u = stage[i];
        unsigned hi = (unsigned)(u >> 32);
        int bkt = hi >> 16;
        unsigned long long lkey = hi & 0xFFFFu;
        int pos = lbase[bkt] + (i - lofs[bkt]);
        if (pos < BCAP)
            part[(size_t)bkt * BCAP + pos] = (lkey << 32) | (u & 0xffffffffULL);
    }
}

// ---------------- CSR pass 2: per-bucket counting sort, runs PADDED to 8 ----------------
// 392 blocks, ~73 KB LDS -> 2 blocks/CU. srcs fully written to PBCAP (pad+tail
// = DUMMY) so any in-bucket read hits a valid index.
static __global__ __launch_bounds__(512) void k_bsort(const unsigned long long* __restrict__ part,
                                                      const int* __restrict__ gcur,
                                                      int* __restrict__ offs,
                                                      int* __restrict__ cnt,
                                                      int* __restrict__ srcs) {
    __shared__ int lhist[NKEY];      // 5 KB
    __shared__ int lscan[NKEY];      // 5 KB
    __shared__ int sscan[256];       // 1 KB
    __shared__ int lsrc[PBCAP];      // 60 KB
    int b = blockIdx.x;
    int t = threadIdx.x;
    int n = gcur[b]; if (n > BCAP) n = BCAP;
    const unsigned long long* reg = part + (size_t)b * BCAP;

    for (int k = t; k < NKEY; k += 512) lhist[k] = 0;
    __syncthreads();
    for (int i = t; i < n; i += 512)
        atomicAdd(&lhist[(int)(reg[i] >> 32)], 1);
    __syncthreads();

    // exclusive scan over PADDED counts (1280 = 256 threads x 5 keys)
    int loc[5]; int s5 = 0;
    if (t < 256) {
#pragma unroll
        for (int j = 0; j < 5; j++) { loc[j] = s5; s5 += (lhist[t * 5 + j] + 7) & ~7; }
        sscan[t] = s5;
    }
    __syncthreads();
    for (int off = 1; off < 256; off <<= 1) {
        int x = (t >= off && t < 256) ? sscan[t - off] : 0;
        __syncthreads();
        if (t < 256) sscan[t] += x;
        __syncthreads();
    }
    if (t < 256) {
        int excl = sscan[t] - s5;
#pragma unroll
        for (int j = 0; j < 5; j++) lscan[t * 5 + j] = excl + loc[j];
    }
    __syncthreads();

    int base = b * PBCAP;
    if (t < 256) {
#pragma unroll
        for (int j = 0; j < 5; j++) {
            int k = t * 5 + j;
            int segid = b * NKEY + k;
            if (segid < SEG) {
                cnt[segid]  = lhist[k];
                offs[segid] = base + lscan[k];
            }
        }
    }
    __syncthreads();
    // reset cursors + dummy-fill ENTIRE bucket region
    for (int k = t; k < NKEY; k += 512) lhist[k] = 0;
    for (int i = t; i < PBCAP; i += 512) lsrc[i] = DUMMY;
    __syncthreads();
    for (int i = t; i < n; i += 512) {
        unsigned long long u = reg[i];
        int k = (int)(u >> 32);
        int pos = lscan[k] + atomicAdd(&lhist[k], 1);
        if (pos < PBCAP) lsrc[pos] = (int)(u & 0xffffffffULL);
    }
    __syncthreads();
    for (int i = t; i < PBCAP; i += 512) srcs[base + i] = lsrc[i];
}

// ---------------- fp16 layer-0 table + dummy rows of ht1..ht4 + srcs slack -------
static __global__ __launch_bounds__(256) void k_pad(const float* __restrict__ x,
                                                    __half* __restrict__ ht0,
                                                    __half* __restrict__ ht1,
                                                    __half* __restrict__ ht2,
                                                    __half* __restrict__ ht3,
                                                    __half* __restrict__ ht4,
                                                    int* __restrict__ srcs) {
    int tid = blockIdx.x * 256 + threadIdx.x;
    if (tid < (N_NODES + 1) * 32) {
        int nd = tid >> 5, ii = tid & 31;
        float v = (nd < N_NODES && ii < 4) ? x[(nd << 2) + ii] : 0.f;
        ht0[tid] = __float2half(v);
    } else {
        int r = tid - (N_NODES + 1) * 32;
        if (r < 128) {
            __half* hp = (r < 32) ? ht1 : (r < 64) ? ht2 : (r < 96) ? ht3 : ht4;
            hp[N_NODES * 32 + (r & 31)] = __float2half(0.f);   // dummy rows
        } else if (r < 144) srcs[NBUCK * PBCAP + (r - 128)] = DUMMY;  // slack
    }
}

// ---------------- weight prep: fp16 MFMA B-fragments, 4 RGCN layers ----------------
// Per-layer block = 5*2*512 = 5120 halves. idx = ((l*5+s)*2+tile)*512 + lane*8+j
// holds W_l[k = s*32+(lane>>4)*8+j][o = tile*16+(lane&15)]. Exactly 20480 threads.
static __global__ __launch_bounds__(256) void k_wprepB(
    const float* __restrict__ ba0, const float* __restrict__ ro0,
    const float* __restrict__ ba1, const float* __restrict__ ro1,
    const float* __restrict__ ba2, const float* __restrict__ ro2,
    const float* __restrict__ ba3, const float* __restrict__ ro3,
    __half* __restrict__ Wb) {
    int idx = blockIdx.x * 256 + threadIdx.x;   // < 20480
    int j    = idx & 7;
    int lane = (idx >> 3) & 63;
    int tile = (idx >> 9) & 1;
    int ls   = idx >> 10;                       // l*5 + s, < 20
    int l    = ls / 5;
    int s    = ls - l * 5;
    const float* basis = (l == 0) ? ba0 : (l == 1) ? ba1 : (l == 2) ? ba2 : ba3;
    const float* root  = (l == 0) ? ro0 : (l == 1) ? ro1 : (l == 2) ? ro2 : ro3;
    int in_c = (l == 0) ? 4 : HID;
    int k = s * 32 + ((lane >> 4) << 3) + j;
    int o = tile * 16 + (lane & 15);
    float v;
    if (k < 128) {
        int b = k >> 5, ii = k & 31;
        v = (ii < in_c) ? basis[(b * in_c + ii) * HID + o] : 0.f;
    } else {
        int ii = k - 128;
        v = (ii < in_c) ? root[ii * HID + o] : 0.f;
    }
    Wb[idx] = __float2half(v);
}

// ---------------- weight prep: w1 [256x128] fp16 B-fragments for the MLP ----------
static __global__ __launch_bounds__(256) void k_wprepM(const float* __restrict__ w1,
                                                       __half* __restrict__ Wm) {
    int idx = blockIdx.x * 256 + threadIdx.x;   // < 32768
    int j    = idx & 7;
    int lane = (idx >> 3) & 63;
    int s    = (idx >> 9) & 7;
    int tile = idx >> 12;                       // < 8
    int k = s * 32 + ((lane >> 4) << 3) + j;
    int o = tile * 16 + (lane & 15);
    Wm[idx] = __float2half(w1[k * 128 + o]);
}

// ---------------- fused RGCN layer ----------------
// Phase 1: quarter-wave = 1 node, p = dim pair, __half2 dword gathers from a
// DENSE fp16 table (stride 32: one node row = one 64B line -> max L2 density).
// 8-padded runs, per-run comp fold. Deposits K=160 aggregate as fp16 into
// sAgg16[16][176].
// Phase 2: [16x160]x[160x32] via 5x mfma_f32_16x16x32_f16 per 16-col tile;
// epilogue bias+tanh, single dense fp16 store (hout).
static __global__ __launch_bounds__(256, 8) void k_layer(
    const __half2* __restrict__ tab, const int* __restrict__ offs,
    const int* __restrict__ cnt, const int* __restrict__ srcs,
    const float* __restrict__ comp, const __half* __restrict__ Wbl,
    const float* __restrict__ bias, __half* __restrict__ hout) {
    __shared__ __align__(16) __half sAgg16[16 * 176];   // 5.5 KB
    int t = threadIdx.x;
    int wave = t >> 6, q = (t >> 4) & 3, p = t & 15;

    float4 cw0 = *(const float4*)(comp + 0);        // SGPR-resident
    float4 cw1 = *(const float4*)(comp + 4);
    float4 cw2 = *(const float4*)(comp + 8);
    float4 cw3 = *(const float4*)(comp + 12);
    float4 cw4 = *(const float4*)(comp + 16);

    int n = blockIdx.x * 16 + wave * 4 + q;         // N_NODES = 6250*16
    int s5 = n * N_REL;
    int oo[6], cc[5];
#pragma unroll
    for (int r = 0; r < 5; r++) { oo[r] = offs[s5 + r]; cc[r] = cnt[s5 + r]; }
    oo[5] = oo[4] + ((cc[4] + 7) & ~7);             // padded end

    __half2 selfh = tab[n * 16 + p];
    float a0x = 0.f, a0y = 0.f, a1x = 0.f, a1y = 0.f;
    float a2x = 0.f, a2y = 0.f, a3x = 0.f, a3y = 0.f;

#pragma unroll
    for (int r = 0; r < 5; r++) {
        int pR = oo[r], pr = oo[r + 1] - pR;
        const int* sp = srcs + pR;                  // 32B-aligned
        int4 e0 = *(const int4*)(sp);               // per-quad broadcast
        int4 e1 = *(const int4*)(sp + 4);
        __half2 g0 = tab[e0.x * 16 + p], g1 = tab[e0.y * 16 + p];
        __half2 g2 = tab[e0.z * 16 + p], g3 = tab[e0.w * 16 + p];
        __half2 g4 = tab[e1.x * 16 + p], g5 = tab[e1.y * 16 + p];
        __half2 g6 = tab[e1.z * 16 + p], g7 = tab[e1.w * 16 + p];
        __half2 sb = __hadd2(__hadd2(__hadd2(g0, g1), __hadd2(g2, g3)),
                             __hadd2(__hadd2(g4, g5), __hadd2(g6, g7)));
        float2 bf = __half22float2(sb);
        float Sx = bf.x, Sy = bf.y;
        for (int s8 = 8; s8 < pr; s8 += 8) {        // residual batches (~20%)
            int4 f0 = *(const int4*)(sp + s8);
            int4 f1 = *(const int4*)(sp + s8 + 4);
            __half2 h0 = tab[f0.x * 16 + p], h1 = tab[f0.y * 16 + p];
            __half2 h2 = tab[f0.z * 16 + p], h3 = tab[f0.w * 16 + p];
            __half2 h4 = tab[f1.x * 16 + p], h5 = tab[f1.y * 16 + p];
            __half2 h6 = tab[f1.z * 16 + p], h7 = tab[f1.w * 16 + p];
            __half2 rb = __hadd2(__hadd2(__hadd2(h0, h1), __hadd2(h2, h3)),
                                 __hadd2(__hadd2(h4, h5), __hadd2(h6, h7)));
            float2 rf = __half22float2(rb);
            Sx += rf.x; Sy += rf.y;
        }
        int cr = cc[r];
        float ic = (cr > 0) ? __builtin_amdgcn_rcpf((float)cr) : 0.f;
        float scx = Sx * ic, scy = Sy * ic;
        float4 cw = (r == 0) ? cw0 : (r == 1) ? cw1 : (r == 2) ? cw2
                  : (r == 3) ? cw3 : cw4;           // resolved at unroll
        a0x += cw.x * scx; a0y += cw.x * scy;
        a1x += cw.y * scx; a1y += cw.y * scy;
        a2x += cw.z * scx; a2y += cw.z * scy;
        a3x += cw.w * scx; a3y += cw.w * scy;
    }
    int nl = wave * 4 + q;
    __half2* row = (__half2*)(sAgg16 + nl * 176);   // k/2 index
    row[p]      = __float22half2_rn(make_float2(a0x, a0y));   // k = 0..31
    row[16 + p] = __float22half2_rn(make_float2(a1x, a1y));   // k = 32..63
    row[32 + p] = __float22half2_rn(make_float2(a2x, a2y));   // k = 64..95
    row[48 + p] = __float22half2_rn(make_float2(a3x, a3y));   // k = 96..127
    row[64 + p] = selfh;                                      // k = 128..159
    __syncthreads();

    // phase 2: [16x160] x [160x32] via 5x mfma_f32_16x16x32_f16 per tile
    if (wave < 2) {
        int lane = t & 63;
        floatx4 acc = {0.f, 0.f, 0.f, 0.f};
        const __half* aBase = sAgg16 + (lane & 15) * 176 + ((lane >> 4) << 3);
        const __half* bBase = Wbl + wave * 512 + lane * 8;
#pragma unroll
        for (int s = 0; s < 5; s++) {
            half8 a = *(const half8*)(aBase + s * 32);
            half8 b = *(const half8*)(bBase + s * 1024);
            acc = __builtin_amdgcn_mfma_f32_16x16x32_f16(a, b, acc, 0, 0, 0);
        }
        int o = wave * 16 + (lane & 15);
        float bi = bias[o];
#pragma unroll
        for (int r = 0; r < 4; r++) {
            int node = blockIdx.x * 16 + ((lane >> 4) << 2) + r;
            hout[node * 32 + o] = __float2half(tanhf(acc[r] + bi));
        }
    }
}

// ---------------- final MLP via MFMA: 16 graphs/block ----------------
// g-vector concat gathered straight from the 4 dense tables: lane = (table
// lt = lane>>4, dim-pair lp = lane&15) -> coalesced 64B chunks.
static __global__ __launch_bounds__(256) void k_mlp(
    const __half* __restrict__ h1, const __half* __restrict__ h2,
    const __half* __restrict__ h3, const __half* __restrict__ h4,
    const int* __restrict__ uidx, const int* __restrict__ iidx,
    const __half* __restrict__ Wm, const float* __restrict__ b1,
    const float* __restrict__ w2, const float* __restrict__ b2,
    float* __restrict__ out) {
    __shared__ __align__(16) __half sg[16 * 264];   // 8.25 KB
    __shared__ float sacc[4][16];
    int t = threadIdx.x, wave = t >> 6, lane = t & 63;
    int g0 = blockIdx.x * 16;
    int lt = lane >> 4, lp = lane & 15;
    const __half* htab = (lt == 0) ? h1 : (lt == 1) ? h2 : (lt == 2) ? h3 : h4;
#pragma unroll
    for (int gg2 = 0; gg2 < 4; gg2++) {
        int gg = wave * 4 + gg2;
        int g = g0 + gg;
        int u = uidx[g], it = iidx[g];
        __half2* dst = (__half2*)(sg + gg * 264);
        dst[lt * 16 + lp]      = ((const __half2*)(htab + u * 32))[lp];
        dst[64 + lt * 16 + lp] = ((const __half2*)(htab + it * 32))[lp];
    }
    __syncthreads();
    floatx4 acc0 = {0.f, 0.f, 0.f, 0.f}, acc1 = {0.f, 0.f, 0.f, 0.f};
    const __half* aBase = sg + (lane & 15) * 264 + ((lane >> 4) << 3);
    const __half* bB0 = Wm + (wave * 2 + 0) * 4096 + lane * 8;
    const __half* bB1 = Wm + (wave * 2 + 1) * 4096 + lane * 8;
#pragma unroll
    for (int s = 0; s < 8; s++) {
        half8 a  = *(const half8*)(aBase + s * 32);
        half8 f0 = *(const half8*)(bB0 + s * 512);
        half8 f1 = *(const half8*)(bB1 + s * 512);
        acc0 = __builtin_amdgcn_mfma_f32_16x16x32_f16(a, f0, acc0, 0, 0, 0);
        acc1 = __builtin_amdgcn_mfma_f32_16x16x32_f16(a, f1, acc1, 0, 0, 0);
    }
    int o0 = wave * 32 + (lane & 15);
    int o1 = o0 + 16;
    float b10 = b1[o0], b11 = b1[o1], w20 = w2[o0], w21 = w2[o1];
#pragma unroll
    for (int r = 0; r < 4; r++) {
        float z0 = fmaxf(acc0[r] + b10, 0.f);
        float z1 = fmaxf(acc1[r] + b11, 0.f);
        float v = z0 * w20 + z1 * w21;
#pragma unroll
        for (int off = 1; off < 16; off <<= 1) v += __shfl_xor(v, off);
        if ((lane & 15) == 0) sacc[wave][((lane >> 4) << 2) + r] = v;
    }
    __syncthreads();
    if (t < 16)
        out[g0 + t] = sacc[0][t] + sacc[1][t] + sacc[2][t] + sacc[3][t] + b2[0];
}

// ---------------- launcher ----------------
extern "C" void kernel_launch(void* const* d_in, const int* in_sizes, int n_in,
                              void* d_out, int out_size, void* d_ws, size_t ws_size,
                              hipStream_t stream) {
    const float* x  = (const float*)d_in[0];
    const int*   ei = (const int*)d_in[1];
    const int*   et = (const int*)d_in[2];
    const int*   ui = (const int*)d_in[3];
    const int*   ii = (const int*)d_in[4];
    const float* w1 = (const float*)d_in[21];
    const float* b1 = (const float*)d_in[22];
    const float* w2 = (const float*)d_in[23];
    const float* b2 = (const float*)d_in[24];

    // workspace layout (bytes, 128-aligned). Total ~60.2 MB; guard proven in R1.
    char* ws = (char*)d_ws;
    if (ws_size < 92167680UL) return;
    int*    gcur = (int*)(ws + 0);              // [392]
    int*    offs = (int*)(ws + 2048);           // [500000]
    int*    cnt  = (int*)(ws + 2002176);        // [500000]
    int*    srcs = (int*)(ws + 4002304);        // [392*15360] + 16 slack
    __half* Wb   = (__half*)(ws + 28086912);    // [20480] fp16 RGCN B-frags
    __half* Wm   = (__half*)(ws + 28127872);    // [32768] fp16 MLP B-frags
    __half* ht0  = (__half*)(ws + 28193536);    // [100001*32] fp16 dense
    __half* ht1  = (__half*)(ws + 34593664);    // [100001*32]
    __half* ht2  = (__half*)(ws + 40993792);    // [100001*32]
    __half* ht3  = (__half*)(ws + 47393920);    // [100001*32]
    __half* ht4  = (__half*)(ws + 53794048);    // [100001*32], ends 60.2 MB
    // part aliases ht1..ht4 + tail (dead after k_bsort; layers run later)
    unsigned long long* part = (unsigned long long*)(ws + 34593664);  // 32.1 MB

    hipMemsetAsync(gcur, 0, NBUCK * 4, stream);

    k_part<<<(N_EDGES + PTILE - 1) / PTILE, 256, 0, stream>>>(ei, et, gcur, part);
    k_bsort<<<NBUCK, 512, 0, stream>>>(part, gcur, offs, cnt, srcs);
    k_pad<<<12501, 256, 0, stream>>>(x, ht0, ht1, ht2, ht3, ht4, srcs);
    k_wprepB<<<80, 256, 0, stream>>>(           // 80*256 = 20480 = 4 layers * 5120
        (const float*)d_in[5],  (const float*)d_in[7],
        (const float*)d_in[9],  (const float*)d_in[11],
        (const float*)d_in[13], (const float*)d_in[15],
        (const float*)d_in[17], (const float*)d_in[19], Wb);
    k_wprepM<<<128, 256, 0, stream>>>(w1, Wm);  // 128*256 = 32768

    __half* tabs[5] = {ht0, ht1, ht2, ht3, ht4};
    for (int l = 0; l < 4; l++) {
        const float* comp = (const float*)d_in[6 + 4 * l];
        const float* bias = (const float*)d_in[8 + 4 * l];
        k_layer<<<6250, 256, 0, stream>>>((const __half2*)tabs[l], offs, cnt,
                                          srcs, comp, Wb + l * 5120, bias,
                                          tabs[l + 1]);
    }
    k_mlp<<<256, 256, 0, stream>>>(ht1, ht2, ht3, ht4, ui, ii, Wm, b1, w2, b2,
                                   (float*)d_out);
}

// Round 13
// 348.078 us; speedup vs baseline: 1.1551x; 1.0156x over previous
//
#include <hip/hip_runtime.h>
#include <hip/hip_bf16.h>
#include <hip/hip_fp16.h>

#define N_NODES 100000
#define N_EDGES 3200000
#define N_GRAPHS 4096
#define N_REL 5
#define N_BASES 4
#define HID 32
#define SEG (N_NODES*N_REL)
#define DUMMY N_NODES            // extra node whose fp16 feature row is all-zero

#define NBUCK 392                // buckets of 256 dst nodes
#define BCAP  10240              // part-record capacity per bucket (mean 8163)
#define PBCAP 15360              // padded srcs capacity per bucket (mean ~12.9K)
#define NKEY  1280               // 256 nodes * 5 rels
#define PTILE 4096               // edges per k_part block (32 KB stage -> 4 blocks/CU)

typedef _Float16 half8 __attribute__((ext_vector_type(8)));
typedef float floatx4 __attribute__((ext_vector_type(4)));

// ---------------- CSR pass 1: partition edges into dst-range buckets ----------------
// In-block counting sort: LDS histogram (edges held in registers) ->
// bucket-contiguous LDS staging -> sequential copy-out (write-combined runs).
// PTILE=4096 keeps LDS ~38 KB -> 4 blocks/CU (vs R12's 2 at 13% occupancy).
static __global__ __launch_bounds__(256) void k_part(const int* __restrict__ ei,
                                                     const int* __restrict__ et,
                                                     int* __restrict__ gcur,
                                                     unsigned long long* __restrict__ part) {
    __shared__ unsigned long long stage[PTILE];     // 32 KB
    __shared__ int hist[NBUCK];
    __shared__ int lofs[NBUCK];
    __shared__ int lbase[NBUCK];
    __shared__ int sscan[256];
    int t = threadIdx.x;
    int e0 = blockIdx.x * PTILE;
    int tile_n = N_EDGES - e0; if (tile_n > PTILE) tile_n = PTILE;

    for (int k = t; k < NBUCK; k += 256) hist[k] = 0;
    __syncthreads();
    // pass A: load 16 edges/thread into registers + LDS histogram
    int src[16], bkt[16], lkey[16];
#pragma unroll
    for (int j = 0; j < 16; j++) {
        int e = e0 + j * 256 + t;
        if (e < N_EDGES) {
            int s = ei[e];
            int d = ei[N_EDGES + e];
            int r = et[e];
            src[j] = s; bkt[j] = d >> 8; lkey[j] = ((d & 255) * 5) + r;
            atomicAdd(&hist[bkt[j]], 1);
        } else bkt[j] = -1;
    }
    __syncthreads();
    // exclusive scan over 392 buckets: thread t owns slots 2t, 2t+1
    int h0 = (2 * t     < NBUCK) ? hist[2 * t]     : 0;
    int h1 = (2 * t + 1 < NBUCK) ? hist[2 * t + 1] : 0;
    int s2 = h0 + h1;
    sscan[t] = s2;
    __syncthreads();
    for (int off = 1; off < 256; off <<= 1) {
        int xv = (t >= off) ? sscan[t - off] : 0;
        __syncthreads();
        sscan[t] += xv;
        __syncthreads();
    }
    int excl = sscan[t] - s2;
    if (2 * t     < NBUCK) lofs[2 * t]     = excl;
    if (2 * t + 1 < NBUCK) lofs[2 * t + 1] = excl + h0;
    // reserve global space per bucket
    for (int k = t; k < NBUCK; k += 256) lbase[k] = atomicAdd(&gcur[k], hist[k]);
    __syncthreads();
    for (int k = t; k < NBUCK; k += 256) hist[k] = 0;   // reuse as cursor
    __syncthreads();
    // pass B: scatter registers into bucket-ordered LDS staging
#pragma unroll
    for (int j = 0; j < 16; j++) {
        if (bkt[j] >= 0) {
            int rank = atomicAdd(&hist[bkt[j]], 1);
            stage[lofs[bkt[j]] + rank] =
                ((unsigned long long)(unsigned)((bkt[j] << 16) | lkey[j]) << 32)
                | (unsigned)src[j];
        }
    }
    __syncthreads();
    // pass C: sequential copy-out — per-bucket runs land coalesced
    for (int i = t; i < tile_n; i += 256) {
        unsigned long long u = stage[i];
        unsigned hi = (unsigned)(u >> 32);
        int bb = hi >> 16;
        unsigned long long lk = hi & 0xFFFFu;
        int pos = lbase[bb] + (i - lofs[bb]);
        if (pos < BCAP)
            part[(size_t)bb * BCAP + pos] = (lk << 32) | (u & 0xffffffffULL);
    }
}

// ---------------- CSR pass 2: per-bucket counting sort, runs PADDED to 8 ----------------
// 1024 threads x 392 blocks, ~71 KB LDS -> 2 blocks x 16 waves = 32 waves/CU.
// Writes back ptot+16 entries (pad slots DUMMY); empty-run prefetches read at
// most 32B past data, covered by the +16 margin / global slack.
static __global__ __launch_bounds__(1024) void k_bsort(const unsigned long long* __restrict__ part,
                                                       const int* __restrict__ gcur,
                                                       int* __restrict__ offs,
                                                       int* __restrict__ cnt,
                                                       int* __restrict__ srcs) {
    __shared__ int lhist[NKEY];      // 5 KB
    __shared__ int lscan[NKEY];      // 5 KB
    __shared__ int sscan[256];       // 1 KB
    __shared__ int lsrc[PBCAP];      // 60 KB
    int b = blockIdx.x;
    int t = threadIdx.x;
    int n = gcur[b]; if (n > BCAP) n = BCAP;
    const unsigned long long* reg = part + (size_t)b * BCAP;

    for (int k = t; k < NKEY; k += 1024) lhist[k] = 0;
    __syncthreads();
    for (int i = t; i < n; i += 1024)
        atomicAdd(&lhist[(int)(reg[i] >> 32)], 1);
    __syncthreads();

    // exclusive scan over PADDED counts (1280 = 256 threads x 5 keys)
    int loc[5]; int s5 = 0;
    if (t < 256) {
#pragma unroll
        for (int j = 0; j < 5; j++) { loc[j] = s5; s5 += (lhist[t * 5 + j] + 7) & ~7; }
        sscan[t] = s5;
    }
    __syncthreads();
    for (int off = 1; off < 256; off <<= 1) {
        int x = (t >= off && t < 256) ? sscan[t - off] : 0;
        __syncthreads();
        if (t < 256) sscan[t] += x;
        __syncthreads();
    }
    if (t < 256) {
        int excl = sscan[t] - s5;
#pragma unroll
        for (int j = 0; j < 5; j++) lscan[t * 5 + j] = excl + loc[j];
    }
    __syncthreads();
    int ptot = sscan[255]; if (ptot > PBCAP) ptot = PBCAP;
    int pout = ptot + 16; if (pout > PBCAP) pout = PBCAP;

    int base = b * PBCAP;
    if (t < 256) {
#pragma unroll
        for (int j = 0; j < 5; j++) {
            int k = t * 5 + j;
            int segid = b * NKEY + k;
            if (segid < SEG) {
                cnt[segid]  = lhist[k];
                offs[segid] = base + lscan[k];
            }
        }
    }
    __syncthreads();
    // reset cursors + dummy-fill the written region
    for (int k = t; k < NKEY; k += 1024) lhist[k] = 0;
    for (int i = t; i < pout; i += 1024) lsrc[i] = DUMMY;
    __syncthreads();
    for (int i = t; i < n; i += 1024) {
        unsigned long long u = reg[i];
        int k = (int)(u >> 32);
        int pos = lscan[k] + atomicAdd(&lhist[k], 1);
        if (pos < PBCAP) lsrc[pos] = (int)(u & 0xffffffffULL);
    }
    __syncthreads();
    for (int i = t; i < pout; i += 1024) srcs[base + i] = lsrc[i];
}

// ---------------- fp16 layer-0 table + dummy rows of ht1..ht4 + srcs slack -------
static __global__ __launch_bounds__(256) void k_pad(const float* __restrict__ x,
                                                    __half* __restrict__ ht0,
                                                    __half* __restrict__ ht1,
                                                    __half* __restrict__ ht2,
                                                    __half* __restrict__ ht3,
                                                    __half* __restrict__ ht4,
                                                    int* __restrict__ srcs) {
    int tid = blockIdx.x * 256 + threadIdx.x;
    if (tid < (N_NODES + 1) * 32) {
        int nd = tid >> 5, ii = tid & 31;
        float v = (nd < N_NODES && ii < 4) ? x[(nd << 2) + ii] : 0.f;
        ht0[tid] = __float2half(v);
    } else {
        int r = tid - (N_NODES + 1) * 32;
        if (r < 128) {
            __half* hp = (r < 32) ? ht1 : (r < 64) ? ht2 : (r < 96) ? ht3 : ht4;
            hp[N_NODES * 32 + (r & 31)] = __float2half(0.f);   // dummy rows
        } else if (r < 144) srcs[NBUCK * PBCAP + (r - 128)] = DUMMY;  // slack
    }
}

// ---------------- weight prep: fp16 MFMA B-fragments, 4 RGCN layers ----------------
// Per-layer block = 5*2*512 = 5120 halves. idx = ((l*5+s)*2+tile)*512 + lane*8+j
// holds W_l[k = s*32+(lane>>4)*8+j][o = tile*16+(lane&15)]. Exactly 20480 threads.
static __global__ __launch_bounds__(256) void k_wprepB(
    const float* __restrict__ ba0, const float* __restrict__ ro0,
    const float* __restrict__ ba1, const float* __restrict__ ro1,
    const float* __restrict__ ba2, const float* __restrict__ ro2,
    const float* __restrict__ ba3, const float* __restrict__ ro3,
    __half* __restrict__ Wb) {
    int idx = blockIdx.x * 256 + threadIdx.x;   // < 20480
    int j    = idx & 7;
    int lane = (idx >> 3) & 63;
    int tile = (idx >> 9) & 1;
    int ls   = idx >> 10;                       // l*5 + s, < 20
    int l    = ls / 5;
    int s    = ls - l * 5;
    const float* basis = (l == 0) ? ba0 : (l == 1) ? ba1 : (l == 2) ? ba2 : ba3;
    const float* root  = (l == 0) ? ro0 : (l == 1) ? ro1 : (l == 2) ? ro2 : ro3;
    int in_c = (l == 0) ? 4 : HID;
    int k = s * 32 + ((lane >> 4) << 3) + j;
    int o = tile * 16 + (lane & 15);
    float v;
    if (k < 128) {
        int b = k >> 5, ii = k & 31;
        v = (ii < in_c) ? basis[(b * in_c + ii) * HID + o] : 0.f;
    } else {
        int ii = k - 128;
        v = (ii < in_c) ? root[ii * HID + o] : 0.f;
    }
    Wb[idx] = __float2half(v);
}

// ---------------- weight prep: w1 [256x128] fp16 B-fragments for the MLP ----------
static __global__ __launch_bounds__(256) void k_wprepM(const float* __restrict__ w1,
                                                       __half* __restrict__ Wm) {
    int idx = blockIdx.x * 256 + threadIdx.x;   // < 32768
    int j    = idx & 7;
    int lane = (idx >> 3) & 63;
    int s    = (idx >> 9) & 7;
    int tile = idx >> 12;                       // < 8
    int k = s * 32 + ((lane >> 4) << 3) + j;
    int o = tile * 16 + (lane & 15);
    Wm[idx] = __float2half(w1[k * 128 + o]);
}

// ---------------- fused RGCN layer ----------------
// Phase 1: quarter-wave = 1 node, p = dim pair, __half2 dword gathers from a
// DENSE fp16 table (stride 32: one node row = one 64B line -> max L2 density).
// 8-padded runs, per-run comp fold. Deposits K=160 aggregate as fp16 into
// sAgg16[16][176].
// Phase 2: [16x160]x[160x32] via 5x mfma_f32_16x16x32_f16 per 16-col tile;
// epilogue bias+tanh, single dense fp16 store (hout).
static __global__ __launch_bounds__(256, 8) void k_layer(
    const __half2* __restrict__ tab, const int* __restrict__ offs,
    const int* __restrict__ cnt, const int* __restrict__ srcs,
    const float* __restrict__ comp, const __half* __restrict__ Wbl,
    const float* __restrict__ bias, __half* __restrict__ hout) {
    __shared__ __align__(16) __half sAgg16[16 * 176];   // 5.5 KB
    int t = threadIdx.x;
    int wave = t >> 6, q = (t >> 4) & 3, p = t & 15;

    float4 cw0 = *(const float4*)(comp + 0);        // SGPR-resident
    float4 cw1 = *(const float4*)(comp + 4);
    float4 cw2 = *(const float4*)(comp + 8);
    float4 cw3 = *(const float4*)(comp + 12);
    float4 cw4 = *(const float4*)(comp + 16);

    int n = blockIdx.x * 16 + wave * 4 + q;         // N_NODES = 6250*16
    int s5 = n * N_REL;
    int oo[6], cc[5];
#pragma unroll
    for (int r = 0; r < 5; r++) { oo[r] = offs[s5 + r]; cc[r] = cnt[s5 + r]; }
    oo[5] = oo[4] + ((cc[4] + 7) & ~7);             // padded end

    __half2 selfh = tab[n * 16 + p];
    float a0x = 0.f, a0y = 0.f, a1x = 0.f, a1y = 0.f;
    float a2x = 0.f, a2y = 0.f, a3x = 0.f, a3y = 0.f;

#pragma unroll
    for (int r = 0; r < 5; r++) {
        int pR = oo[r], pr = oo[r + 1] - pR;
        const int* sp = srcs + pR;                  // 32B-aligned
        int4 e0 = *(const int4*)(sp);               // per-quad broadcast
        int4 e1 = *(const int4*)(sp + 4);
        __half2 g0 = tab[e0.x * 16 + p], g1 = tab[e0.y * 16 + p];
        __half2 g2 = tab[e0.z * 16 + p], g3 = tab[e0.w * 16 + p];
        __half2 g4 = tab[e1.x * 16 + p], g5 = tab[e1.y * 16 + p];
        __half2 g6 = tab[e1.z * 16 + p], g7 = tab[e1.w * 16 + p];
        __half2 sb = __hadd2(__hadd2(__hadd2(g0, g1), __hadd2(g2, g3)),
                             __hadd2(__hadd2(g4, g5), __hadd2(g6, g7)));
        float2 bf = __half22float2(sb);
        float Sx = bf.x, Sy = bf.y;
        for (int s8 = 8; s8 < pr; s8 += 8) {        // residual batches (~20%)
            int4 f0 = *(const int4*)(sp + s8);
            int4 f1 = *(const int4*)(sp + s8 + 4);
            __half2 h0 = tab[f0.x * 16 + p], h1 = tab[f0.y * 16 + p];
            __half2 h2 = tab[f0.z * 16 + p], h3 = tab[f0.w * 16 + p];
            __half2 h4 = tab[f1.x * 16 + p], h5 = tab[f1.y * 16 + p];
            __half2 h6 = tab[f1.z * 16 + p], h7 = tab[f1.w * 16 + p];
            __half2 rb = __hadd2(__hadd2(__hadd2(h0, h1), __hadd2(h2, h3)),
                                 __hadd2(__hadd2(h4, h5), __hadd2(h6, h7)));
            float2 rf = __half22float2(rb);
            Sx += rf.x; Sy += rf.y;
        }
        int cr = cc[r];
        float ic = (cr > 0) ? __builtin_amdgcn_rcpf((float)cr) : 0.f;
        float scx = Sx * ic, scy = Sy * ic;
        float4 cw = (r == 0) ? cw0 : (r == 1) ? cw1 : (r == 2) ? cw2
                  : (r == 3) ? cw3 : cw4;           // resolved at unroll
        a0x += cw.x * scx; a0y += cw.x * scy;
        a1x += cw.y * scx; a1y += cw.y * scy;
        a2x += cw.z * scx; a2y += cw.z * scy;
        a3x += cw.w * scx; a3y += cw.w * scy;
    }
    int nl = wave * 4 + q;
    __half2* row = (__half2*)(sAgg16 + nl * 176);   // k/2 index
    row[p]      = __float22half2_rn(make_float2(a0x, a0y));   // k = 0..31
    row[16 + p] = __float22half2_rn(make_float2(a1x, a1y));   // k = 32..63
    row[32 + p] = __float22half2_rn(make_float2(a2x, a2y));   // k = 64..95
    row[48 + p] = __float22half2_rn(make_float2(a3x, a3y));   // k = 96..127
    row[64 + p] = selfh;                                      // k = 128..159
    __syncthreads();

    // phase 2: [16x160] x [160x32] via 5x mfma_f32_16x16x32_f16 per tile
    if (wave < 2) {
        int lane = t & 63;
        floatx4 acc = {0.f, 0.f, 0.f, 0.f};
        const __half* aBase = sAgg16 + (lane & 15) * 176 + ((lane >> 4) << 3);
        const __half* bBase = Wbl + wave * 512 + lane * 8;
#pragma unroll
        for (int s = 0; s < 5; s++) {
            half8 a = *(const half8*)(aBase + s * 32);
            half8 b = *(const half8*)(bBase + s * 1024);
            acc = __builtin_amdgcn_mfma_f32_16x16x32_f16(a, b, acc, 0, 0, 0);
        }
        int o = wave * 16 + (lane & 15);
        float bi = bias[o];
#pragma unroll
        for (int r = 0; r < 4; r++) {
            int node = blockIdx.x * 16 + ((lane >> 4) << 2) + r;
            hout[node * 32 + o] = __float2half(tanhf(acc[r] + bi));
        }
    }
}

// ---------------- final MLP via MFMA: 16 graphs/block ----------------
static __global__ __launch_bounds__(256) void k_mlp(
    const __half* __restrict__ h1, const __half* __restrict__ h2,
    const __half* __restrict__ h3, const __half* __restrict__ h4,
    const int* __restrict__ uidx, const int* __restrict__ iidx,
    const __half* __restrict__ Wm, const float* __restrict__ b1,
    const float* __restrict__ w2, const float* __restrict__ b2,
    float* __restrict__ out) {
    __shared__ __align__(16) __half sg[16 * 264];   // 8.25 KB
    __shared__ float sacc[4][16];
    int t = threadIdx.x, wave = t >> 6, lane = t & 63;
    int g0 = blockIdx.x * 16;
    int lt = lane >> 4, lp = lane & 15;
    const __half* htab = (lt == 0) ? h1 : (lt == 1) ? h2 : (lt == 2) ? h3 : h4;
#pragma unroll
    for (int gg2 = 0; gg2 < 4; gg2++) {
        int gg = wave * 4 + gg2;
        int g = g0 + gg;
        int u = uidx[g], it = iidx[g];
        __half2* dst = (__half2*)(sg + gg * 264);
        dst[lt * 16 + lp]      = ((const __half2*)(htab + u * 32))[lp];
        dst[64 + lt * 16 + lp] = ((const __half2*)(htab + it * 32))[lp];
    }
    __syncthreads();
    floatx4 acc0 = {0.f, 0.f, 0.f, 0.f}, acc1 = {0.f, 0.f, 0.f, 0.f};
    const __half* aBase = sg + (lane & 15) * 264 + ((lane >> 4) << 3);
    const __half* bB0 = Wm + (wave * 2 + 0) * 4096 + lane * 8;
    const __half* bB1 = Wm + (wave * 2 + 1) * 4096 + lane * 8;
#pragma unroll
    for (int s = 0; s < 8; s++) {
        half8 a  = *(const half8*)(aBase + s * 32);
        half8 f0 = *(const half8*)(bB0 + s * 512);
        half8 f1 = *(const half8*)(bB1 + s * 512);
        acc0 = __builtin_amdgcn_mfma_f32_16x16x32_f16(a, f0, acc0, 0, 0, 0);
        acc1 = __builtin_amdgcn_mfma_f32_16x16x32_f16(a, f1, acc1, 0, 0, 0);
    }
    int o0 = wave * 32 + (lane & 15);
    int o1 = o0 + 16;
    float b10 = b1[o0], b11 = b1[o1], w20 = w2[o0], w21 = w2[o1];
#pragma unroll
    for (int r = 0; r < 4; r++) {
        float z0 = fmaxf(acc0[r] + b10, 0.f);
        float z1 = fmaxf(acc1[r] + b11, 0.f);
        float v = z0 * w20 + z1 * w21;
#pragma unroll
        for (int off = 1; off < 16; off <<= 1) v += __shfl_xor(v, off);
        if ((lane & 15) == 0) sacc[wave][((lane >> 4) << 2) + r] = v;
    }
    __syncthreads();
    if (t < 16)
        out[g0 + t] = sacc[0][t] + sacc[1][t] + sacc[2][t] + sacc[3][t] + b2[0];
}

// ---------------- launcher ----------------
extern "C" void kernel_launch(void* const* d_in, const int* in_sizes, int n_in,
                              void* d_out, int out_size, void* d_ws, size_t ws_size,
                              hipStream_t stream) {
    const float* x  = (const float*)d_in[0];
    const int*   ei = (const int*)d_in[1];
    const int*   et = (const int*)d_in[2];
    const int*   ui = (const int*)d_in[3];
    const int*   ii = (const int*)d_in[4];
    const float* w1 = (const float*)d_in[21];
    const float* b1 = (const float*)d_in[22];
    const float* w2 = (const float*)d_in[23];
    const float* b2 = (const float*)d_in[24];

    // workspace layout (bytes, 128-aligned). Total ~60.2 MB; guard proven in R1.
    char* ws = (char*)d_ws;
    if (ws_size < 92167680UL) return;
    int*    gcur = (int*)(ws + 0);              // [392]
    int*    offs = (int*)(ws + 2048);           // [500000]
    int*    cnt  = (int*)(ws + 2002176);        // [500000]
    int*    srcs = (int*)(ws + 4002304);        // [392*15360] + 16 slack
    __half* Wb   = (__half*)(ws + 28086912);    // [20480] fp16 RGCN B-frags
    __half* Wm   = (__half*)(ws + 28127872);    // [32768] fp16 MLP B-frags
    __half* ht0  = (__half*)(ws + 28193536);    // [100001*32] fp16 dense
    __half* ht1  = (__half*)(ws + 34593664);    // [100001*32]
    __half* ht2  = (__half*)(ws + 40993792);    // [100001*32]
    __half* ht3  = (__half*)(ws + 47393920);    // [100001*32]
    __half* ht4  = (__half*)(ws + 53794048);    // [100001*32], ends 60.2 MB
    // part aliases ht1..ht4 + tail (dead after k_bsort; layers run later)
    unsigned long long* part = (unsigned long long*)(ws + 34593664);  // 32.1 MB

    hipMemsetAsync(gcur, 0, NBUCK * 4, stream);

    k_part<<<(N_EDGES + PTILE - 1) / PTILE, 256, 0, stream>>>(ei, et, gcur, part);
    k_bsort<<<NBUCK, 1024, 0, stream>>>(part, gcur, offs, cnt, srcs);
    k_pad<<<12501, 256, 0, stream>>>(x, ht0, ht1, ht2, ht3, ht4, srcs);
    k_wprepB<<<80, 256, 0, stream>>>(           // 80*256 = 20480 = 4 layers * 5120
        (const float*)d_in[5],  (const float*)d_in[7],
        (const float*)d_in[9],  (const float*)d_in[11],
        (const float*)d_in[13], (const float*)d_in[15],
        (const float*)d_in[17], (const float*)d_in[19], Wb);
    k_wprepM<<<128, 256, 0, stream>>>(w1, Wm);  // 128*256 = 32768

    __half* tabs[5] = {ht0, ht1, ht2, ht3, ht4};
    for (int l = 0; l < 4; l++) {
        const float* comp = (const float*)d_in[6 + 4 * l];
        const float* bias = (const float*)d_in[8 + 4 * l];
        k_layer<<<6250, 256, 0, stream>>>((const __half2*)tabs[l], offs, cnt,
                                          srcs, comp, Wb + l * 5120, bias,
                                          tabs[l + 1]);
    }
    k_mlp<<<256, 256, 0, stream>>>(ht1, ht2, ht3, ht4, ui, ii, Wm, b1, w2, b2,
                                   (float*)d_out);
}